// Round 5
// baseline (4587.955 us; speedup 1.0000x reference)
//
#include <hip/hip_runtime.h>

#define TLEN 256
#define DD 8
#define HH 128
#define NTHREADS 512

typedef __attribute__((ext_vector_type(8))) _Float16 half8;
typedef __attribute__((ext_vector_type(4))) float f32x4;

#define LOSCALE 65536.0f
#define LOINV   (1.0f/65536.0f)
#define TSTRIDE 24576   // bytes per tile in act[] (6 bufs x 4096)

static __device__ __forceinline__ float tanh_fast(float x){
  float cx = fminf(fmaxf(x, -9.01f), 9.01f);
  float e = __builtin_amdgcn_exp2f(cx * 2.885390081777927f); // exp(2x)
  return 1.0f - 2.0f * __builtin_amdgcn_rcpf(e + 1.0f);
}

// ---- pack W2 into MFMA fragment order: hi (unscaled) + lo (x65536), fp16.
// frag f = (w*8+ct)*4+kt, lane l holds W2[kt*32+(l>>4)*8+j][w*128+ct*16+(l&15)], j=0..7
__global__ void pack_w2_kernel(const float* __restrict__ W2, half8* __restrict__ ws){
  int gid = blockIdx.x * 256 + threadIdx.x;
  int l = gid & 63;
  int f = gid >> 6;                           // 0..255
  int kt = f & 3, ct = (f >> 2) & 7, w = f >> 5;
  int col = w*128 + ct*16 + (l & 15);
  int kb  = kt*32 + (l >> 4)*8;
  half8 vh, vl;
  #pragma unroll
  for (int j = 0; j < 8; j++){
    float v = W2[(kb + j)*1024 + col];
    _Float16 h = (_Float16)v;
    vh[j] = h;
    vl[j] = (_Float16)((v - (float)h) * LOSCALE);
  }
  ws[f*64 + l] = vh;            // hi region: frags [0,256)
  ws[(256 + f)*64 + l] = vl;    // lo region
}

// One block = 32 batch rows (2 tiles of 16) for the whole T recurrence. 8 waves.
// Wave w owns cols [16w,16w+16) of h1/h2 and rows (c) [128w,128w+128) of G3^T.
__global__ __launch_bounds__(NTHREADS, 2) void ncde_kernel(
    const float* __restrict__ x, const float* __restrict__ Win, const float* __restrict__ bin,
    const float* __restrict__ W0, const float* __restrict__ b0v, const float* __restrict__ W1,
    const float* __restrict__ b1v, const float* __restrict__ W2, const float* __restrict__ b2v,
    const half8* __restrict__ wsw2, float* __restrict__ out)
{
  // act arena: [tile 0/1][buf 0..5][2048 ushort]; bufs: 0 zh,1 zl,2 h1h,3 h1l,4 h2h,5 h2l
  __shared__ unsigned short act[2*6*2048];   // 48 KB

  const int t    = threadIdx.x;
  const int lane = t & 63;
  const int w    = t >> 6;        // wave 0..7
  const int lg   = lane >> 4;     // lane group 0..3
  const int ln   = lane & 15;
  const int b0blk = blockIdx.x * 32;
  const int dbase = (lg & 1) * 4;

  // ---- one-time: W0/W1 fragments -> registers (hi + lo*65536)
  half8 w0h[4], w0l[4], w1h[4], w1l[4];
  #pragma unroll
  for (int kt = 0; kt < 4; kt++){
    half8 vh, vl, uh, ul;
    #pragma unroll
    for (int j = 0; j < 8; j++){
      int krow = kt*32 + (lane >> 4)*8 + j;
      float v0 = W0[krow*HH + w*16 + ln];
      _Float16 h0 = (_Float16)v0; vh[j] = h0; vl[j] = (_Float16)((v0 - (float)h0)*LOSCALE);
      float v1 = W1[krow*HH + w*16 + ln];
      _Float16 h1 = (_Float16)v1; uh[j] = h1; ul[j] = (_Float16)((v1 - (float)h1)*LOSCALE);
    }
    w0h[kt] = vh; w0l[kt] = vl; w1h[kt] = uh; w1l[kt] = ul;
  }

  // ---- one-time: W2 hi fragments -> registers
  half8 w2f[8][4];
  #pragma unroll
  for (int ct = 0; ct < 8; ct++)
    #pragma unroll
    for (int kt = 0; kt < 4; kt++)
      w2f[ct][kt] = wsw2[((w*8 + ct)*4 + kt)*64 + lane];
  const half8* wsL = wsw2 + 256*64;

  const float b0r = b0v[w*16 + ln];
  const float w0L = W0[128*HH + w*16 + ln];
  const float b1r = b1v[w*16 + ln];
  f32x4 b2r4[8];
  #pragma unroll
  for (int ct = 0; ct < 8; ct++)
    b2r4[ct] = *(const f32x4*)(b2v + w*128 + ct*16 + lg*4);

  // ---- precomputed LDS byte offsets
  unsigned ard[4];                     // A-frag reads (all three GEMMs, same layout)
  #pragma unroll
  for (int kt = 0; kt < 4; kt++)
    ard[kt] = (unsigned)ln*256u + (((unsigned)(kt*64 + lg*16)) ^ (((unsigned)(ln & 7)) << 4));
  unsigned sst[4];                     // h1/h2 split-store
  #pragma unroll
  for (int r = 0; r < 4; r++){
    int row = lg*4 + r;
    sst[r] = (unsigned)row*256u + ((((unsigned)(w*16 + ln))*2u) ^ (((unsigned)(row & 7)) << 4));
  }
  unsigned zst[8];                     // z writeback (even-lg lanes)
  #pragma unroll
  for (int ct = 0; ct < 8; ct++){
    int h = w*16 + ct*2 + (lg >> 1);
    zst[ct] = (unsigned)ln*256u + (((unsigned)h*2u) ^ (((unsigned)(ln & 7)) << 4));
  }
  unsigned ovr[8]; unsigned orow[8];   // out-write: LDS read addr + global row offset
  #pragma unroll
  for (int i = 0; i < 8; i++){
    int o = t + i*NTHREADS;
    int br = o >> 7, h = o & 127, brt = br & 15;
    ovr[i]  = (unsigned)(br >> 4)*TSTRIDE + (unsigned)brt*256u +
              (((unsigned)h*2u) ^ (((unsigned)(brt & 7)) << 4));
    orow[i] = (unsigned)(b0blk + br)*(TLEN*HH) + (unsigned)h;
  }

  const float* xb0 = x + (size_t)(b0blk + ln)*(TLEN*DD) + dbase;
  const float* xb1 = x + (size_t)(b0blk + 16 + ln)*(TLEN*DD) + dbase;
  f32x4 xprev0 = *(const f32x4*)xb0;
  f32x4 xprev1 = *(const f32x4*)xb1;

  // ---- z0 = x[:,0,:] @ Win + bin (exact fp32), split-stored fp16 hi/lo
  for (int o = t; o < 4096; o += NTHREADS){
    int br = o >> 7, h = o & 127, brt = br & 15;
    float acc = bin[h];
    const float* xr = x + (size_t)(b0blk + br)*(TLEN*DD);
    #pragma unroll
    for (int d = 0; d < DD; d++) acc += xr[d] * Win[d*HH + h];
    unsigned byte = (unsigned)(br >> 4)*TSTRIDE + (unsigned)brt*256u +
                    (((unsigned)h*2u) ^ (((unsigned)(brt & 7)) << 4));
    _Float16 hv = (_Float16)acc;
    *(_Float16*)((char*)act + byte)        = hv;
    *(_Float16*)((char*)act + byte + 4096) = (_Float16)(acc - (float)hv);
  }
  __syncthreads();

  // z accumulators: zreg[g][ct] = z[b=ln(+16g)][h = w*16+ct*2+(lg>>1)]
  float zreg[2][8];
  #pragma unroll
  for (int g = 0; g < 2; g++)
    #pragma unroll
    for (int ct = 0; ct < 8; ct++){
      unsigned byte = zst[ct] + g*TSTRIDE;
      zreg[g][ct] = (float)*(_Float16*)((char*)act + byte)
                  + (float)*(_Float16*)((char*)act + byte + 4096);
    }

  // out[:,0,:]
  #pragma unroll
  for (int i = 0; i < 8; i++)
    out[orow[i]] = (float)*(_Float16*)((char*)act + ovr[i])
                 + (float)*(_Float16*)((char*)act + ovr[i] + 4096);

  const float inv = 1.0f / 255.0f;

  for (int k = 0; k < TLEN - 1; k++){
    float tk = (float)k * inv;

    f32x4 xn0 = *(const f32x4*)(xb0 + (size_t)(k + 1)*DD);
    f32x4 xn1 = *(const f32x4*)(xb1 + (size_t)(k + 1)*DD);

    // ---- GEMM1: h1 = relu([z,t] @ W0 + b0)   (2 tiles interleaved)
    {
      f32x4 ah0={0,0,0,0}, al0={0,0,0,0}, ac0={0,0,0,0};
      f32x4 ah1={0,0,0,0}, al1={0,0,0,0}, ac1={0,0,0,0};
      #pragma unroll
      for (int kt = 0; kt < 4; kt++){
        half8 zh0 = *(const half8*)((const char*)act + ard[kt]);
        half8 zl0 = *(const half8*)((const char*)act + ard[kt] + 4096);
        half8 zh1 = *(const half8*)((const char*)act + ard[kt] + TSTRIDE);
        half8 zl1 = *(const half8*)((const char*)act + ard[kt] + TSTRIDE + 4096);
        ah0 = __builtin_amdgcn_mfma_f32_16x16x32_f16(zh0, w0h[kt], ah0, 0, 0, 0);
        ah1 = __builtin_amdgcn_mfma_f32_16x16x32_f16(zh1, w0h[kt], ah1, 0, 0, 0);
        al0 = __builtin_amdgcn_mfma_f32_16x16x32_f16(zl0, w0h[kt], al0, 0, 0, 0);
        al1 = __builtin_amdgcn_mfma_f32_16x16x32_f16(zl1, w0h[kt], al1, 0, 0, 0);
        ac0 = __builtin_amdgcn_mfma_f32_16x16x32_f16(zh0, w0l[kt], ac0, 0, 0, 0);
        ac1 = __builtin_amdgcn_mfma_f32_16x16x32_f16(zh1, w0l[kt], ac1, 0, 0, 0);
      }
      float c0 = b0r + tk * w0L;
      #pragma unroll
      for (int r = 0; r < 4; r++){
        float v0 = fmaxf(ah0[r] + al0[r] + ac0[r]*LOINV + c0, 0.0f);
        float v1 = fmaxf(ah1[r] + al1[r] + ac1[r]*LOINV + c0, 0.0f);
        _Float16 h0 = (_Float16)v0, h1 = (_Float16)v1;
        *(_Float16*)((char*)act + sst[r] + 2*4096)            = h0;
        *(_Float16*)((char*)act + sst[r] + 3*4096)            = (_Float16)(v0 - (float)h0);
        *(_Float16*)((char*)act + sst[r] + TSTRIDE + 2*4096)  = h1;
        *(_Float16*)((char*)act + sst[r] + TSTRIDE + 3*4096)  = (_Float16)(v1 - (float)h1);
      }
    }
    __syncthreads(); // B1

    // ---- GEMM2: h2 = relu(h1 @ W1 + b1)
    {
      f32x4 ah0={0,0,0,0}, al0={0,0,0,0}, ac0={0,0,0,0};
      f32x4 ah1={0,0,0,0}, al1={0,0,0,0}, ac1={0,0,0,0};
      #pragma unroll
      for (int kt = 0; kt < 4; kt++){
        half8 zh0 = *(const half8*)((const char*)act + ard[kt] + 2*4096);
        half8 zl0 = *(const half8*)((const char*)act + ard[kt] + 3*4096);
        half8 zh1 = *(const half8*)((const char*)act + ard[kt] + TSTRIDE + 2*4096);
        half8 zl1 = *(const half8*)((const char*)act + ard[kt] + TSTRIDE + 3*4096);
        ah0 = __builtin_amdgcn_mfma_f32_16x16x32_f16(zh0, w1h[kt], ah0, 0, 0, 0);
        ah1 = __builtin_amdgcn_mfma_f32_16x16x32_f16(zh1, w1h[kt], ah1, 0, 0, 0);
        al0 = __builtin_amdgcn_mfma_f32_16x16x32_f16(zl0, w1h[kt], al0, 0, 0, 0);
        al1 = __builtin_amdgcn_mfma_f32_16x16x32_f16(zl1, w1h[kt], al1, 0, 0, 0);
        ac0 = __builtin_amdgcn_mfma_f32_16x16x32_f16(zh0, w1l[kt], ac0, 0, 0, 0);
        ac1 = __builtin_amdgcn_mfma_f32_16x16x32_f16(zh1, w1l[kt], ac1, 0, 0, 0);
      }
      #pragma unroll
      for (int r = 0; r < 4; r++){
        float v0 = fmaxf(ah0[r] + al0[r] + ac0[r]*LOINV + b1r, 0.0f);
        float v1 = fmaxf(ah1[r] + al1[r] + ac1[r]*LOINV + b1r, 0.0f);
        _Float16 h0 = (_Float16)v0, h1 = (_Float16)v1;
        *(_Float16*)((char*)act + sst[r] + 4*4096)            = h0;
        *(_Float16*)((char*)act + sst[r] + 5*4096)            = (_Float16)(v0 - (float)h0);
        *(_Float16*)((char*)act + sst[r] + TSTRIDE + 4*4096)  = h1;
        *(_Float16*)((char*)act + sst[r] + TSTRIDE + 5*4096)  = (_Float16)(v1 - (float)h1);
      }
    }
    // prefetch ct=0 W2-lo frags (global; overlaps barrier)
    half8 wl[2][4];
    #pragma unroll
    for (int kt = 0; kt < 4; kt++) wl[0][kt] = wsL[((w*8 + 0)*4 + kt)*64 + lane];
    __syncthreads(); // B2

    // ---- GEMM3 transposed: G3^T = W2^T x h2^T, + tanh + einsum
    half8 ahh[2][4], ahl[2][4];
    #pragma unroll
    for (int g = 0; g < 2; g++)
      #pragma unroll
      for (int kt = 0; kt < 4; kt++){
        ahh[g][kt] = *(const half8*)((const char*)act + ard[kt] + g*TSTRIDE + 4*4096);
        ahl[g][kt] = *(const half8*)((const char*)act + ard[kt] + g*TSTRIDE + 5*4096);
      }
    f32x4 dxr0 = xn0 - xprev0; xprev0 = xn0;
    f32x4 dxr1 = xn1 - xprev1; xprev1 = xn1;

    #pragma unroll
    for (int ct = 0; ct < 8; ct++){
      // issue next ct's W2-lo loads first (double-buffered)
      if (ct < 7){
        #pragma unroll
        for (int kt = 0; kt < 4; kt++)
          wl[(ct + 1) & 1][kt] = wsL[((w*8 + ct + 1)*4 + kt)*64 + lane];
      }
      f32x4 h30={0,0,0,0}, l30={0,0,0,0}, c30={0,0,0,0};
      f32x4 h31={0,0,0,0}, l31={0,0,0,0}, c31={0,0,0,0};
      #pragma unroll
      for (int kt = 0; kt < 4; kt++){
        h30 = __builtin_amdgcn_mfma_f32_16x16x32_f16(w2f[ct][kt], ahh[0][kt], h30, 0, 0, 0);
        h31 = __builtin_amdgcn_mfma_f32_16x16x32_f16(w2f[ct][kt], ahh[1][kt], h31, 0, 0, 0);
        l30 = __builtin_amdgcn_mfma_f32_16x16x32_f16(w2f[ct][kt], ahl[0][kt], l30, 0, 0, 0);
        l31 = __builtin_amdgcn_mfma_f32_16x16x32_f16(w2f[ct][kt], ahl[1][kt], l31, 0, 0, 0);
        c30 = __builtin_amdgcn_mfma_f32_16x16x32_f16(wl[ct & 1][kt], ahh[0][kt], c30, 0, 0, 0);
        c31 = __builtin_amdgcn_mfma_f32_16x16x32_f16(wl[ct & 1][kt], ahh[1][kt], c31, 0, 0, 0);
      }
      float s0 = 0.0f, s1 = 0.0f;
      #pragma unroll
      for (int r = 0; r < 4; r++){
        s0 += tanh_fast(h30[r] + l30[r] + c30[r]*LOINV + b2r4[ct][r]) * dxr0[r];
        s1 += tanh_fast(h31[r] + l31[r] + c31[r]*LOINV + b2r4[ct][r]) * dxr1[r];
      }
      s0 += __shfl_xor(s0, 16, 64);
      s1 += __shfl_xor(s1, 16, 64);
      zreg[0][ct] += s0;
      zreg[1][ct] += s1;
    }

    // z writeback (even-lg lanes own distinct (b,h))
    if ((lg & 1) == 0){
      #pragma unroll
      for (int g = 0; g < 2; g++)
        #pragma unroll
        for (int ct = 0; ct < 8; ct++){
          float v = zreg[g][ct];
          _Float16 hv = (_Float16)v;
          unsigned byte = zst[ct] + g*TSTRIDE;
          *(_Float16*)((char*)act + byte)        = hv;
          *(_Float16*)((char*)act + byte + 4096) = (_Float16)(v - (float)hv);
        }
    }
    __syncthreads(); // B3

    // out[:,k+1,:] — coalesced
    {
      float* outk = out + (size_t)(k + 1)*HH;
      #pragma unroll
      for (int i = 0; i < 8; i++)
        outk[orow[i]] = (float)*(_Float16*)((char*)act + ovr[i])
                      + (float)*(_Float16*)((char*)act + ovr[i] + 4096);
    }
  }
}

extern "C" void kernel_launch(void* const* d_in, const int* in_sizes, int n_in,
                              void* d_out, int out_size, void* d_ws, size_t ws_size,
                              hipStream_t stream) {
  const float* x   = (const float*)d_in[0];
  const float* Win = (const float*)d_in[1];
  const float* bin = (const float*)d_in[2];
  const float* W0  = (const float*)d_in[3];
  const float* b0  = (const float*)d_in[4];
  const float* W1  = (const float*)d_in[5];
  const float* b1  = (const float*)d_in[6];
  const float* W2  = (const float*)d_in[7];
  const float* b2  = (const float*)d_in[8];
  float* out = (float*)d_out;
  half8* wsw2 = (half8*)d_ws;   // 512 KB: 256 hi frags + 256 lo frags

  pack_w2_kernel<<<dim3(64), dim3(256), 0, stream>>>(W2, wsw2);
  ncde_kernel<<<dim3(32), dim3(NTHREADS), 0, stream>>>(
      x, Win, bin, W0, b0, W1, b1, W2, b2, wsw2, out);
}